// Round 2
// baseline (224.417 us; speedup 1.0000x reference)
//
#include <hip/hip_runtime.h>

#define MAX_SEP 512
#define T_ROWS 1025          // 2*MAX_SEP+1
#define H 160
#define B 4
#define S 256
#define HV 40                // H/4 float4 per h-row
#define TG 257               // ceil(1025/4)

typedef float v4f __attribute__((ext_vector_type(4)));

// ---------------------------------------------------------------------------
// Kernel 1: Y[q][t][h] = sum_kk pe_q[t][kk] * W[h][q*H+kk]   (+ bias folded
// into q==0 table). Reads W rows directly (160 consecutive floats per thread,
// vectorizes to dwordx4; W = 410 KB, L2-resident). Each thread computes 4
// consecutive t for one (q,h) to amortize the W-row read.
// ---------------------------------------------------------------------------
__global__ __launch_bounds__(256) void compute_y(
        const float* __restrict__ pe0, const float* __restrict__ pe1,
        const float* __restrict__ pe2, const float* __restrict__ pe3,
        const float* __restrict__ W,   const float* __restrict__ bias,
        float* __restrict__ Y) {
    int e = blockIdx.x * 256 + threadIdx.x;       // over (q, tg, h)
    if (e >= 4 * TG * H) return;
    int h  = e % H;
    int tg = (e / H) % TG;
    int q  = e / (H * TG);
    const float* pe = (q == 0) ? pe0 : (q == 1) ? pe1 : (q == 2) ? pe2 : pe3;

    int t0 = tg * 4;
    int t1 = min(t0 + 1, T_ROWS - 1);             // clamp reads; stores guarded
    int t2 = min(t0 + 2, T_ROWS - 1);
    int t3 = min(t0 + 3, T_ROWS - 1);
    const float* p0 = pe + (size_t)t0 * H;
    const float* p1 = pe + (size_t)t1 * H;
    const float* p2 = pe + (size_t)t2 * H;
    const float* p3 = pe + (size_t)t3 * H;
    const float* wrow = W + (size_t)h * (4 * H) + q * H;  // 160 consecutive

    float a0 = 0.f, a1 = 0.f, a2 = 0.f, a3 = 0.f;
#pragma unroll 8
    for (int kk = 0; kk < H; ++kk) {
        float w = wrow[kk];
        a0 = fmaf(p0[kk], w, a0);
        a1 = fmaf(p1[kk], w, a1);
        a2 = fmaf(p2[kk], w, a2);
        a3 = fmaf(p3[kk], w, a3);
    }
    float bb = (q == 0) ? bias[h] : 0.f;
    float* yq = Y + ((size_t)q * T_ROWS + t0) * H + h;    // coalesced over h
    yq[0] = a0 + bb;
    if (t0 + 1 < T_ROWS) yq[H]     = a1 + bb;
    if (t0 + 2 < T_ROWS) yq[2 * H] = a2 + bb;
    if (t0 + 3 < T_ROWS) yq[3 * H] = a3 + bb;
}

// ---------------------------------------------------------------------------
// Kernel 2: out[b,i,j,h] = ReLU(Y0[d_ss]+Y1[d_se]+Y2[d_es]+Y3[d_ee])[h]
// 4 blocks per (b,i) row (4096 blocks total -> better latency hiding for the
// ~200-cyc L2-hit gather loads). Non-temporal stores keep the 2.6 MB Y table
// L2-resident against the 167.8 MB write-once output stream.
// ---------------------------------------------------------------------------
__global__ __launch_bounds__(256) void gather_add(
        const int* __restrict__ pos_s, const int* __restrict__ pos_e,
        const float* __restrict__ Y, float* __restrict__ out) {
    int blk = blockIdx.x;             // 0..4095
    int bi  = blk >> 2;               // (b,i) row
    int q4  = blk & 3;                // quarter of the row
    int bb  = bi >> 8;                // / S
    int i   = bi & (S - 1);
    int tid = threadIdx.x;

    __shared__ int ls[S], le[S];
    ls[tid] = pos_s[bb * S + tid];
    le[tid] = pos_e[bb * S + tid];
    __syncthreads();

    int psi = ls[i];
    int pei = le[i];

    const v4f* __restrict__ Y4 = (const v4f*)Y;
    v4f* __restrict__ out4 = (v4f*)out + (size_t)bi * (S * HV);

    // quarter-row: 2560 float4 elements, 10 iterations of 256 threads
#pragma unroll 2
    for (int it = 0; it < 10; ++it) {
        int base = q4 * 2560 + it * 256 + tid;
        int j  = base / HV;           // const divide -> magic mul
        int hv = base - j * HV;
        int pj_s = ls[j], pj_e = le[j];
        int d0 = psi - pj_s + MAX_SEP;
        int d1 = psi - pj_e + MAX_SEP;
        int d2 = pei - pj_s + MAX_SEP;
        int d3 = pei - pj_e + MAX_SEP;
        v4f v0 = Y4[(size_t)(0 * T_ROWS + d0) * HV + hv];
        v4f v1 = Y4[(size_t)(1 * T_ROWS + d1) * HV + hv];
        v4f v2 = Y4[(size_t)(2 * T_ROWS + d2) * HV + hv];
        v4f v3 = Y4[(size_t)(3 * T_ROWS + d3) * HV + hv];
        v4f s = v0 + v1 + v2 + v3;
        v4f r;
        r.x = fmaxf(s.x, 0.f);
        r.y = fmaxf(s.y, 0.f);
        r.z = fmaxf(s.z, 0.f);
        r.w = fmaxf(s.w, 0.f);
        __builtin_nontemporal_store(r, &out4[base]);   // dwordx4 nt
    }
}

// ---------------------------------------------------------------------------
extern "C" void kernel_launch(void* const* d_in, const int* in_sizes, int n_in,
                              void* d_out, int out_size, void* d_ws, size_t ws_size,
                              hipStream_t stream) {
    const int*   pos_s = (const int*)d_in[0];
    const int*   pos_e = (const int*)d_in[1];
    const float* pe_ss = (const float*)d_in[2];
    const float* pe_se = (const float*)d_in[3];
    const float* pe_es = (const float*)d_in[4];
    const float* pe_ee = (const float*)d_in[5];
    const float* W     = (const float*)d_in[6];
    const float* bias  = (const float*)d_in[7];
    float* out = (float*)d_out;

    float* Y = (float*)d_ws;                        // 4*1025*160*4 = 2.624 MB

    compute_y<<<(4 * TG * H + 255) / 256, 256, 0, stream>>>(
        pe_ss, pe_se, pe_es, pe_ee, W, bias, Y);
    gather_add<<<4 * B * S, 256, 0, stream>>>(pos_s, pos_e, Y, out);
}